// Round 3
// baseline (129.181 us; speedup 1.0000x reference)
//
#include <hip/hip_runtime.h>
#include <math.h>

#define H 150
#define HP 152        // H padded to multiple of 4
#define G 600         // 4*H
#define STEPS 10
#define NT 256        // rec kernel threads (4 waves, 1 wave/SIMD -> 512 VGPR cap)
#define N3 88         // rows 512..599 handled as bf16 third row on threads t<88
#define W2U 76        // packed u32 per third row (152 bf16)
#define GRIDA 128

__device__ __forceinline__ float sigm(float x) {
    return __builtin_amdgcn_rcpf(1.0f + __expf(-x));
}
__device__ __forceinline__ float ftanh(float x) {
    return 1.0f - 2.0f * __builtin_amdgcn_rcpf(1.0f + __expf(2.0f * x));
}

// ---------------- Kernel A: gx GEMV + W_hh transpose (fp32) + bf16 pack ----------------
__global__ __launch_bounds__(256) void lstm_prep(
    const float* __restrict__ inputx, const float* __restrict__ W_ih,
    const float* __restrict__ W_hh, const float* __restrict__ b_ih,
    const float* __restrict__ b_hh, const int* __restrict__ xp,
    float* __restrict__ gx, float* __restrict__ Wt, unsigned* __restrict__ Wb)
{
    const int b = blockIdx.x;
    if (b < 24) {
        // gx[t*G+g] = W_ih[g,:] . xs[t,:] + b_ih[g] + b_hh[g]
        int gid = b * 256 + threadIdx.x;
        if (gid < STEPS * G) {
            int t = gid / G;
            int g = gid - t * G;
            const float* xrow = inputx + (xp[0] - STEPS + t) * H;
            const float* wrow = W_ih + g * H;
            float a0 = 0.f, a1 = 0.f;
            #pragma unroll
            for (int k = 0; k < H; k += 2) {
                float2 wv = *reinterpret_cast<const float2*>(wrow + k);
                float2 xv = *reinterpret_cast<const float2*>(xrow + k);
                a0 += wv.x * xv.x;
                a1 += wv.y * xv.y;
            }
            gx[gid] = a0 + a1 + b_ih[g] + b_hh[g];
        }
    } else if (b < 120) {
        // Wt[k*G+g] = W_hh[g][k] (k<150), rows 150,151 zero-padded
        for (int i = (b - 24) * 256 + threadIdx.x; i < HP * G; i += 96 * 256) {
            int k = i / G;
            int g = i - k * G;
            Wt[i] = (k < H) ? W_hh[g * H + k] : 0.f;
        }
    } else {
        // Wb[j*N3 + t] = pack_bf16(W_hh[512+t][2j], W_hh[512+t][2j+1]), j<76
        for (int i = (b - 120) * 256 + threadIdx.x; i < W2U * N3; i += 8 * 256) {
            int j = i / N3;
            int t = i - j * N3;
            const float* r = W_hh + (512 + t) * H;
            float lo = (2 * j     < H) ? r[2 * j]     : 0.f;
            float hi = (2 * j + 1 < H) ? r[2 * j + 1] : 0.f;
            unsigned ulo = __float_as_uint(lo);
            unsigned uhi = __float_as_uint(hi);
            ulo = (ulo + 0x7fffu + ((ulo >> 16) & 1u)) >> 16;   // RNE to bf16
            uhi = (uhi + 0x7fffu + ((uhi >> 16) & 1u)) >> 16;
            Wb[i] = (uhi << 16) | (ulo & 0xffffu);
        }
    }
}

// ---------------- Kernel B: 256-thread recurrent loop, all weights in registers ----------------
__global__ __launch_bounds__(NT, 1) void lstm_rec(
    const float* __restrict__ Wt, const unsigned* __restrict__ Wb,
    const float* __restrict__ gx, float* __restrict__ out)
{
    __shared__ __align__(16) float s_h[HP];
    __shared__ float s_c[H];
    __shared__ float s_gate[G];
    __shared__ float s_gx[STEPS * G];

    const int t = threadIdx.x;
    const bool has3 = (t < N3);

    // rows t and 256+t in fp32 registers (coalesced column reads of Wt)
    float w0[HP], w1[HP];
    #pragma unroll
    for (int k = 0; k < HP; ++k) w0[k] = Wt[k * G + t];
    #pragma unroll
    for (int k = 0; k < HP; ++k) w1[k] = Wt[k * G + 256 + t];
    // row 512+t as packed bf16 (threads t<88 only)
    unsigned w2[W2U];
    #pragma unroll
    for (int j = 0; j < W2U; ++j) w2[j] = has3 ? Wb[j * N3 + t] : 0u;

    for (int i = t; i < STEPS * G; i += NT) s_gx[i] = gx[i];

    if (t < HP) s_h[t] = 0.f;     // pads 150,151 stay 0 forever
    if (t < H)  s_c[t] = 0.f;
    __syncthreads();

    #pragma unroll 1
    for (int st = 0; st < STEPS; ++st) {
        float a0 = s_gx[st * G + t];
        float a1 = s_gx[st * G + 256 + t];
        float a2 = has3 ? s_gx[st * G + 512 + t] : 0.f;
        float b0 = 0.f, b1 = 0.f, b2 = 0.f, b3 = 0.f;
        float c0 = 0.f, c1 = 0.f;
        float d0 = 0.f, d1 = 0.f;
        #pragma unroll
        for (int c = 0; c < 38; ++c) {
            float4 hv = *reinterpret_cast<const float4*>(s_h + 4 * c); // broadcast
            b0 += w0[4 * c]     * hv.x;
            b1 += w0[4 * c + 1] * hv.y;
            b2 += w0[4 * c + 2] * hv.z;
            b3 += w0[4 * c + 3] * hv.w;
            c0 += w1[4 * c]     * hv.x + w1[4 * c + 1] * hv.y;
            c1 += w1[4 * c + 2] * hv.z + w1[4 * c + 3] * hv.w;
            unsigned p = w2[2 * c], q = w2[2 * c + 1];
            float p0 = __uint_as_float(p << 16);
            float p1 = __uint_as_float(p & 0xffff0000u);
            float q0 = __uint_as_float(q << 16);
            float q1 = __uint_as_float(q & 0xffff0000u);
            d0 += p0 * hv.x + p1 * hv.y;
            d1 += q0 * hv.z + q1 * hv.w;
        }
        s_gate[t]       = a0 + (b0 + b1) + (b2 + b3);
        s_gate[256 + t] = a1 + (c0 + c1);
        if (has3) s_gate[512 + t] = a2 + (d0 + d1);
        __syncthreads();
        if (t < H) {
            float ig = s_gate[t];
            float fg = s_gate[H + t];
            float gg = s_gate[2 * H + t];
            float og = s_gate[3 * H + t];
            float cn = sigm(fg) * s_c[t] + sigm(ig) * ftanh(gg);
            float hn = sigm(og) * ftanh(cn);
            s_c[t] = cn;
            s_h[t] = hn;
        }
        __syncthreads();
    }

    if (t < H) out[t] = s_h[t];
}

// ---------------- Fallback: fused single kernel (only if ws too small) ----------------
__global__ __launch_bounds__(640) void lstm_fused(
    const float* __restrict__ inputx, const float* __restrict__ W_ih,
    const float* __restrict__ W_hh, const float* __restrict__ b_ih,
    const float* __restrict__ b_hh, const int* __restrict__ xp,
    float* __restrict__ out)
{
    __shared__ float s_h[H];
    __shared__ float s_c[H];
    __shared__ float s_gate[G];
    __shared__ float s_x[STEPS * H];

    const int tid = threadIdx.x;
    if (tid < H) { s_h[tid] = 0.f; s_c[tid] = 0.f; }
    const int x0 = (xp[0] - STEPS) * H;
    for (int i = tid; i < STEPS * H; i += 640) s_x[i] = inputx[x0 + i];
    __syncthreads();

    for (int t = 0; t < STEPS; ++t) {
        if (tid < G) {
            const float* wi = W_ih + tid * H;
            const float* wh = W_hh + tid * H;
            float acc = b_ih[tid] + b_hh[tid];
            for (int k = 0; k < H; ++k)
                acc += wi[k] * s_x[t * H + k] + wh[k] * s_h[k];
            s_gate[tid] = acc;
        }
        __syncthreads();
        if (tid < H) {
            float ig = s_gate[tid], fg = s_gate[H + tid];
            float gg = s_gate[2 * H + tid], og = s_gate[3 * H + tid];
            float cn = sigm(fg) * s_c[tid] + sigm(ig) * ftanh(gg);
            s_c[tid] = cn;
            s_h[tid] = sigm(og) * ftanh(cn);
        }
        __syncthreads();
    }
    if (tid < H) out[tid] = s_h[tid];
}

extern "C" void kernel_launch(void* const* d_in, const int* in_sizes, int n_in,
                              void* d_out, int out_size, void* d_ws, size_t ws_size,
                              hipStream_t stream) {
    const float* inputx = (const float*)d_in[0];
    const float* W_ih   = (const float*)d_in[1];
    const float* W_hh   = (const float*)d_in[2];
    const float* b_ih   = (const float*)d_in[3];
    const float* b_hh   = (const float*)d_in[4];
    const int*   xp     = (const int*)d_in[5];
    float* out = (float*)d_out;

    const size_t need = (size_t)(STEPS * G + HP * G) * sizeof(float)
                      + (size_t)(W2U * N3) * sizeof(unsigned);
    if (ws_size >= need) {
        float*    gx = (float*)d_ws;                     // 6000 f32
        float*    Wt = gx + STEPS * G;                   // 152*600 f32
        unsigned* Wb = (unsigned*)(Wt + HP * G);         // 76*88 u32
        lstm_prep<<<GRIDA, 256, 0, stream>>>(inputx, W_ih, W_hh, b_ih, b_hh,
                                             xp, gx, Wt, Wb);
        lstm_rec<<<1, NT, 0, stream>>>(Wt, Wb, gx, out);
    } else {
        lstm_fused<<<1, 640, 0, stream>>>(inputx, W_ih, W_hh, b_ih, b_hh, xp, out);
    }
}

// Round 5
// 24.928 us; speedup vs baseline: 5.1821x; 5.1821x over previous
//
#include <hip/hip_runtime.h>
#include <hip/hip_fp16.h>
#include <math.h>

#define H 150
#define G 600          // 4*H
#define STEPS 10
#define NT 320         // rec threads: 5 waves, 2/SIMD -> 256 VGPR cap
#define WPR 76         // packed u32 per row (152 fp16, 2 pad)
#define NPK (WPR * G)  // 45600 packed words
#define GRIDA 128

typedef _Float16 half2v __attribute__((ext_vector_type(2)));

__device__ __forceinline__ float sigm(float x) {
    return __builtin_amdgcn_rcpf(1.0f + __expf(-x));
}
__device__ __forceinline__ float ftanh(float x) {
    return 1.0f - 2.0f * __builtin_amdgcn_rcpf(1.0f + __expf(2.0f * x));
}

// acc += dot(packed fp16 pair w, packed fp16 pair h), fp32 accumulate
__device__ __forceinline__ float dot2(float acc, unsigned w, unsigned h) {
#if __has_builtin(__builtin_amdgcn_fdot2)
    return __builtin_amdgcn_fdot2(__builtin_bit_cast(half2v, w),
                                  __builtin_bit_cast(half2v, h), acc, false);
#else
    half2v wv = __builtin_bit_cast(half2v, w);
    half2v hv = __builtin_bit_cast(half2v, h);
    return acc + (float)wv.x * (float)hv.x + (float)wv.y * (float)hv.y;
#endif
}

// f32 -> f16 bits (RNE via hardware convert)
__device__ __forceinline__ unsigned short f2h(float x) {
    _Float16 h = (_Float16)x;
    return __builtin_bit_cast(unsigned short, h);
}

// ---------------- Kernel A: gx GEMV + W_hh -> packed fp16 ----------------
__global__ __launch_bounds__(256) void lstm_prep(
    const float* __restrict__ inputx, const float* __restrict__ W_ih,
    const float* __restrict__ W_hh, const float* __restrict__ b_ih,
    const float* __restrict__ b_hh, const int* __restrict__ xp,
    float* __restrict__ gx, unsigned* __restrict__ Wp)
{
    const int b = blockIdx.x;
    if (b < 24) {
        // gx[t*G+g] = W_ih[g,:] . xs[t,:] + b_ih[g] + b_hh[g]
        int gid = b * 256 + threadIdx.x;
        if (gid < STEPS * G) {
            int t = gid / G;
            int g = gid - t * G;
            const float* xrow = inputx + (xp[0] - STEPS + t) * H;
            const float* wrow = W_ih + g * H;
            float a0 = 0.f, a1 = 0.f;
            #pragma unroll
            for (int k = 0; k < H; k += 2) {
                float2 wv = *reinterpret_cast<const float2*>(wrow + k);
                float2 xv = *reinterpret_cast<const float2*>(xrow + k);
                a0 += wv.x * xv.x;
                a1 += wv.y * xv.y;
            }
            gx[gid] = a0 + a1 + b_ih[g] + b_hh[g];
        }
    } else {
        // Wp[j*G+g] = pack_f16(W_hh[g][2j], W_hh[g][2j+1]); j==75 -> 0 pad
        for (int i = (b - 24) * 256 + threadIdx.x; i < NPK;
             i += (GRIDA - 24) * 256) {
            int g = i / WPR;           // row-major walk: semi-coalesced reads
            int j = i - g * WPR;
            unsigned r = 0;
            if (j < 75) {
                const float* row = W_hh + g * H + 2 * j;
                r = ((unsigned)f2h(row[1]) << 16) | (unsigned)f2h(row[0]);
            }
            Wp[j * G + g] = r;         // [j][g] layout: coalesced in rec
        }
    }
}

// ---------------- Kernel B: 320-thread recurrent loop, fp16 weights in regs ----------------
__global__ __launch_bounds__(NT) void lstm_rec(
    const unsigned* __restrict__ Wp, const float* __restrict__ gx,
    float* __restrict__ out)
{
    __shared__ __align__(16) unsigned short s_hh[2 * WPR];  // 152 fp16 h (2 pads)
    __shared__ float s_gate[G];

    const int t = threadIdx.x;
    const bool rowt = (t < 300);
    const bool actt = (t < H);

    // rows t and 300+t packed fp16 -> registers (coalesced across lanes)
    unsigned w[2 * WPR];
    if (rowt) {
        #pragma unroll
        for (int j = 0; j < WPR; ++j) w[j]       = Wp[j * G + t];
        #pragma unroll
        for (int j = 0; j < WPR; ++j) w[WPR + j] = Wp[j * G + 300 + t];
    }
    // gx columns for both rows, all steps -> registers
    float gxr[2 * STEPS];
    if (rowt) {
        #pragma unroll
        for (int st = 0; st < STEPS; ++st) {
            gxr[2 * st]     = gx[st * G + t];
            gxr[2 * st + 1] = gx[st * G + 300 + t];
        }
    }

    if (t < 2 * WPR) s_hh[t] = 0;
    float c = 0.f;      // cell state lives in activation thread's register
    float hlast = 0.f;
    __syncthreads();

    #pragma unroll 1
    for (int st = 0; st < STEPS; ++st) {
        if (rowt) {
            float a0 = 0.f, a1 = 0.f, a2 = 0.f, a3 = 0.f;   // row t
            float b0 = 0.f, b1 = 0.f, b2 = 0.f, b3 = 0.f;   // row 300+t
            #pragma unroll
            for (int cc = 0; cc < 19; ++cc) {
                float4 hv = *reinterpret_cast<const float4*>(
                    reinterpret_cast<const char*>(s_hh) + 16 * cc); // 8 fp16
                unsigned h0 = __float_as_uint(hv.x);
                unsigned h1 = __float_as_uint(hv.y);
                unsigned h2 = __float_as_uint(hv.z);
                unsigned h3 = __float_as_uint(hv.w);
                a0 = dot2(a0, w[4 * cc],     h0);
                a1 = dot2(a1, w[4 * cc + 1], h1);
                a2 = dot2(a2, w[4 * cc + 2], h2);
                a3 = dot2(a3, w[4 * cc + 3], h3);
                b0 = dot2(b0, w[WPR + 4 * cc],     h0);
                b1 = dot2(b1, w[WPR + 4 * cc + 1], h1);
                b2 = dot2(b2, w[WPR + 4 * cc + 2], h2);
                b3 = dot2(b3, w[WPR + 4 * cc + 3], h3);
            }
            s_gate[t]       = gxr[2 * st]     + (a0 + a1) + (a2 + a3);
            s_gate[300 + t] = gxr[2 * st + 1] + (b0 + b1) + (b2 + b3);
        }
        __syncthreads();
        if (actt) {
            float ig = s_gate[t];
            float fg = s_gate[H + t];
            float gg = s_gate[2 * H + t];
            float og = s_gate[3 * H + t];
            float cn = sigm(fg) * c + sigm(ig) * ftanh(gg);
            float hn = sigm(og) * ftanh(cn);
            c = cn;
            hlast = hn;
            s_hh[t] = f2h(hn);
        }
        __syncthreads();
    }

    if (actt) out[t] = hlast;
}

// ---------------- Fallback: fused single kernel (only if ws too small) ----------------
__global__ __launch_bounds__(640) void lstm_fused(
    const float* __restrict__ inputx, const float* __restrict__ W_ih,
    const float* __restrict__ W_hh, const float* __restrict__ b_ih,
    const float* __restrict__ b_hh, const int* __restrict__ xp,
    float* __restrict__ out)
{
    __shared__ float s_h[H];
    __shared__ float s_c[H];
    __shared__ float s_gate[G];
    __shared__ float s_x[STEPS * H];

    const int tid = threadIdx.x;
    if (tid < H) { s_h[tid] = 0.f; s_c[tid] = 0.f; }
    const int x0 = (xp[0] - STEPS) * H;
    for (int i = tid; i < STEPS * H; i += 640) s_x[i] = inputx[x0 + i];
    __syncthreads();

    for (int t = 0; t < STEPS; ++t) {
        if (tid < G) {
            const float* wi = W_ih + tid * H;
            const float* wh = W_hh + tid * H;
            float acc = b_ih[tid] + b_hh[tid];
            for (int k = 0; k < H; ++k)
                acc += wi[k] * s_x[t * H + k] + wh[k] * s_h[k];
            s_gate[tid] = acc;
        }
        __syncthreads();
        if (tid < H) {
            float ig = s_gate[tid], fg = s_gate[H + tid];
            float gg = s_gate[2 * H + tid], og = s_gate[3 * H + tid];
            float cn = sigm(fg) * s_c[tid] + sigm(ig) * ftanh(gg);
            s_c[tid] = cn;
            s_h[tid] = sigm(og) * ftanh(cn);
        }
        __syncthreads();
    }
    if (tid < H) out[tid] = s_h[tid];
}

extern "C" void kernel_launch(void* const* d_in, const int* in_sizes, int n_in,
                              void* d_out, int out_size, void* d_ws, size_t ws_size,
                              hipStream_t stream) {
    const float* inputx = (const float*)d_in[0];
    const float* W_ih   = (const float*)d_in[1];
    const float* W_hh   = (const float*)d_in[2];
    const float* b_ih   = (const float*)d_in[3];
    const float* b_hh   = (const float*)d_in[4];
    const int*   xp     = (const int*)d_in[5];
    float* out = (float*)d_out;

    const size_t need = (size_t)(STEPS * G) * sizeof(float)
                      + (size_t)NPK * sizeof(unsigned);
    if (ws_size >= need) {
        float*    gx = (float*)d_ws;                 // 6000 f32
        unsigned* Wp = (unsigned*)(gx + STEPS * G);  // 45600 u32
        lstm_prep<<<GRIDA, 256, 0, stream>>>(inputx, W_ih, W_hh, b_ih, b_hh,
                                             xp, gx, Wp);
        lstm_rec<<<1, NT, 0, stream>>>(Wp, gx, out);
    } else {
        lstm_fused<<<1, 640, 0, stream>>>(inputx, W_ih, W_hh, b_ih, b_hh, xp, out);
    }
}